// Round 1
// baseline (1204.693 us; speedup 1.0000x reference)
//
#include <hip/hip_runtime.h>
#include <hip/hip_bf16.h>
#include <math.h>

#define BDIM 16384
#define HDIM 512

typedef __bf16 bf16;
typedef float f32x4 __attribute__((ext_vector_type(4)));
typedef float f32x4v __attribute__((ext_vector_type(4)));
typedef __bf16 bf16x8 __attribute__((ext_vector_type(8)));
typedef __bf16 bf16x4 __attribute__((ext_vector_type(4)));

// ---------------------------------------------------------------- utilities

__device__ __forceinline__ void gload16(const bf16* g, bf16* l) {
  // async global->LDS, 16B per lane; LDS dest = wave-uniform base + lane*16
  __builtin_amdgcn_global_load_lds((const __attribute__((address_space(1))) void*)g,
                                   (__attribute__((address_space(3))) void*)l, 16, 0, 0);
}

__device__ __forceinline__ float gelu_exact(float x) {
  return 0.5f * x * (1.0f + erff(x * 0.70710678118654752f));
}

// ---------------------------------------------------------------- converts

__global__ void cvt_f32_bf16(const float* __restrict__ src, bf16* __restrict__ dst, int n4) {
  int i = blockIdx.x * blockDim.x + threadIdx.x;
  if (i >= n4) return;
  f32x4v v = *(const f32x4v*)(src + i * 4);
  bf16x4 o;
  o[0] = (bf16)v[0]; o[1] = (bf16)v[1]; o[2] = (bf16)v[2]; o[3] = (bf16)v[3];
  *(bf16x4*)(dst + i * 4) = o;
}

// extract the v-projection rows (rows 1024..1535 of each [1536][512] qkv block)
__global__ void cvt_wv(const float* __restrict__ qkv, bf16* __restrict__ dst) {
  int i = blockIdx.x * blockDim.x + threadIdx.x;   // over 6*262144/4
  int e = i * 4;
  int chunk = e >> 18;            // /262144
  int within = e & 262143;
  const float* s = qkv + chunk * 786432 + 524288 + within;
  f32x4v v = *(const f32x4v*)s;
  bf16x4 o;
  o[0] = (bf16)v[0]; o[1] = (bf16)v[1]; o[2] = (bf16)v[2]; o[3] = (bf16)v[3];
  *(bf16x4*)(dst + e) = o;
}

// ---------------------------------------------------------------- GEMM
// C[M][N] = act(A[M][K] @ W[N][K]^T + bias), all bf16, f32 accumulate.
// 128x128 tile, BK=64, 256 threads (4 waves as 2x2), m97 structure.

template<bool GELU>
__launch_bounds__(256)
__global__ void gemm_bf16(const bf16* __restrict__ A, int lda,
                          const bf16* __restrict__ W,
                          const float* __restrict__ bias,
                          bf16* __restrict__ C, int ldc,
                          int K) {
  __shared__ bf16 As[128 * 64];
  __shared__ bf16 Bs[128 * 64];
  const int tid  = threadIdx.x;
  const int lane = tid & 63;
  const int wid  = tid >> 6;
  const int brow = blockIdx.x * 128;
  const int bcol = blockIdx.y * 128;
  const int wr = (wid >> 1) * 64;   // wave row offset in tile
  const int wc = (wid & 1) * 64;    // wave col offset
  const int lr = lane & 15;
  const int kg = lane >> 4;

  f32x4 acc[4][4] = {};

  // staging addresses: thread t covers 8 elems at (row = j*32 + t/8, col = (t%8)*8)
  const bf16* Abase = A + (brow + (tid >> 3)) * lda + ((tid & 7) << 3);
  const bf16* Wbase = W + (bcol + (tid >> 3)) * K + ((tid & 7) << 3);
  bf16* AsDst = As + wid * 512;     // + j*2048 per instruction, wave-uniform
  bf16* BsDst = Bs + wid * 512;

  for (int k0 = 0; k0 < K; k0 += 64) {
#pragma unroll
    for (int j = 0; j < 4; ++j) {
      gload16(Abase + j * 32 * lda + k0, AsDst + j * 2048);
      gload16(Wbase + j * 32 * K + k0, BsDst + j * 2048);
    }
    __syncthreads();   // drains vmcnt before barrier -> tile resident
#pragma unroll
    for (int kk = 0; kk < 64; kk += 32) {
      bf16x8 a[4], b[4];
#pragma unroll
      for (int m = 0; m < 4; ++m)
        a[m] = *(const bf16x8*)(As + (wr + m * 16 + lr) * 64 + kk + kg * 8);
#pragma unroll
      for (int n = 0; n < 4; ++n)
        b[n] = *(const bf16x8*)(Bs + (wc + n * 16 + lr) * 64 + kk + kg * 8);
#pragma unroll
      for (int m = 0; m < 4; ++m)
#pragma unroll
        for (int n = 0; n < 4; ++n)
          acc[m][n] = __builtin_amdgcn_mfma_f32_16x16x32_bf16(a[m], b[n], acc[m][n], 0, 0, 0);
    }
    __syncthreads();   // protect LDS before next-tile overwrite
  }

  // epilogue: bias (+gelu), store bf16. D mapping: col=lane&15, row=(lane>>4)*4+j
  float bv[4];
#pragma unroll
  for (int n = 0; n < 4; ++n) bv[n] = bias[bcol + wc + n * 16 + lr];
#pragma unroll
  for (int m = 0; m < 4; ++m) {
    int row = brow + wr + m * 16 + kg * 4;
#pragma unroll
    for (int n = 0; n < 4; ++n) {
      int col = bcol + wc + n * 16 + lr;
#pragma unroll
      for (int j = 0; j < 4; ++j) {
        float v = acc[m][n][j] + bv[n];
        if (GELU) v = gelu_exact(v);
        C[(row + j) * ldc + col] = (bf16)v;
      }
    }
  }
}

// ---------------------------------------------------------------- add + layernorm
// O = LN(X + R) * g + b, rows of 512, one wave per row

__global__ void add_ln(const bf16* __restrict__ X, const bf16* __restrict__ R,
                       const float* __restrict__ g, const float* __restrict__ b,
                       bf16* __restrict__ O) {
  int lane = threadIdx.x & 63;
  int row = blockIdx.x * 4 + (threadIdx.x >> 6);
  int base = row * HDIM + lane * 8;
  bf16x8 xv = *(const bf16x8*)(X + base);
  bf16x8 rv = *(const bf16x8*)(R + base);
  float v[8], s = 0.f, sq = 0.f;
#pragma unroll
  for (int i = 0; i < 8; ++i) {
    v[i] = (float)xv[i] + (float)rv[i];
    s += v[i]; sq += v[i] * v[i];
  }
#pragma unroll
  for (int off = 32; off > 0; off >>= 1) {
    s += __shfl_xor(s, off);
    sq += __shfl_xor(sq, off);
  }
  float mean = s * (1.f / HDIM);
  float var = sq * (1.f / HDIM) - mean * mean;
  float rstd = rsqrtf(var + 1e-5f);
  f32x4v g0 = *(const f32x4v*)(g + lane * 8);
  f32x4v g1 = *(const f32x4v*)(g + lane * 8 + 4);
  f32x4v b0 = *(const f32x4v*)(b + lane * 8);
  f32x4v b1 = *(const f32x4v*)(b + lane * 8 + 4);
  bf16x8 o;
#pragma unroll
  for (int i = 0; i < 4; ++i) o[i] = (bf16)((v[i] - mean) * rstd * g0[i] + b0[i]);
#pragma unroll
  for (int i = 0; i < 4; ++i) o[4 + i] = (bf16)((v[4 + i] - mean) * rstd * g1[i] + b1[i]);
  *(bf16x8*)(O + base) = o;
}

// ---------------------------------------------------------------- prior MLP (tiny)

__global__ void prior_fc1(const float* __restrict__ emb, const float* __restrict__ w1,
                          const float* __restrict__ b1, float* __restrict__ h) {
  int j = blockIdx.x * 4 + (threadIdx.x >> 6);
  int lane = threadIdx.x & 63;
  const float* wr = w1 + j * 512 + lane * 8;
  const float* e = emb + lane * 8;
  float s = 0.f;
#pragma unroll
  for (int i = 0; i < 8; ++i) s += e[i] * wr[i];
#pragma unroll
  for (int off = 32; off > 0; off >>= 1) s += __shfl_xor(s, off);
  if (lane == 0) h[j] = gelu_exact(s + b1[j]);
}

__global__ void prior_fc2(const float* __restrict__ h, const float* __restrict__ w2,
                          const float* __restrict__ b2, float* __restrict__ p) {
  int j = blockIdx.x * 4 + (threadIdx.x >> 6);
  int lane = threadIdx.x & 63;
  const float* wr = w2 + j * 1024 + lane * 16;
  const float* e = h + lane * 16;
  float s = 0.f;
#pragma unroll
  for (int i = 0; i < 16; ++i) s += e[i] * wr[i];
#pragma unroll
  for (int off = 32; off > 0; off >>= 1) s += __shfl_xor(s, off);
  if (lane == 0) p[j] = s + b2[j];
}

// ---------------------------------------------------------------- final select/blend

__global__ void combine(const float* __restrict__ img, const float* __restrict__ txt,
                        const bf16* __restrict__ gen_t, const bf16* __restrict__ gen_i,
                        const float* __restrict__ prior, const int* __restrict__ mt,
                        const float* __restrict__ rw, float* __restrict__ out) {
  int i4 = blockIdx.x * blockDim.x + threadIdx.x;   // over B*128 float4s
  if (i4 >= BDIM * 128) return;
  int bb = i4 >> 7;
  int c = (i4 & 127) << 2;
  int idx = bb * HDIM + c;
  int m = mt[bb];
  f32x4v iv = *(const f32x4v*)(img + idx);
  f32x4v tv = *(const f32x4v*)(txt + idx);
  f32x4v oi = iv, ot = tv;
  if (m == 2) {
    float r = rw[1];
    bf16x4 gv = *(const bf16x4*)(gen_i + idx);
#pragma unroll
    for (int k = 0; k < 4; ++k) oi[k] = r * iv[k] + (1.f - r) * (float)gv[k];
  } else if (m == 3) {
    oi = *(const f32x4v*)(prior + c);
  }
  if (m == 1) {
    float r = rw[0];
    bf16x4 gv = *(const bf16x4*)(gen_t + idx);
#pragma unroll
    for (int k = 0; k < 4; ++k) ot[k] = r * tv[k] + (1.f - r) * (float)gv[k];
  } else if (m == 3) {
    ot = *(const f32x4v*)(prior + 512 + c);
  }
  *(f32x4v*)(out + idx) = oi;
  *(f32x4v*)(out + BDIM * HDIM + idx) = ot;
}

// ---------------------------------------------------------------- launch

extern "C" void kernel_launch(void* const* d_in, const int* in_sizes, int n_in,
                              void* d_out, int out_size, void* d_ws, size_t ws_size,
                              hipStream_t stream) {
  const float* img  = (const float*)d_in[0];
  const float* txt  = (const float*)d_in[1];
  const float* ipw  = (const float*)d_in[2];
  const float* ipb  = (const float*)d_in[3];
  const float* qkvw = (const float*)d_in[4];
  const float* qkvb = (const float*)d_in[5];
  const float* aow  = (const float*)d_in[6];
  const float* aob  = (const float*)d_in[7];
  const float* ln1g = (const float*)d_in[8];
  const float* ln1b = (const float*)d_in[9];
  const float* ln2g = (const float*)d_in[10];
  const float* ln2b = (const float*)d_in[11];
  const float* f1w  = (const float*)d_in[12];
  const float* f1b  = (const float*)d_in[13];
  const float* f2w  = (const float*)d_in[14];
  const float* f2b  = (const float*)d_in[15];
  const float* opw  = (const float*)d_in[16];
  const float* opb  = (const float*)d_in[17];
  const float* rw   = (const float*)d_in[18];
  const float* pw1  = (const float*)d_in[19];
  const float* pb1  = (const float*)d_in[20];
  const float* pw2  = (const float*)d_in[21];
  const float* pb2  = (const float*)d_in[22];
  const float* pemb = (const float*)d_in[23];
  const int*   mt   = (const int*)d_in[24];
  float* out = (float*)d_out;

  char* ws = (char*)d_ws;
  size_t off = 0;
  auto alloc = [&](size_t bytes) -> char* {
    char* p = ws + off;
    off += (bytes + 255) & ~(size_t)255;
    return p;
  };
  bf16* img_bf = (bf16*)alloc((size_t)BDIM * 512 * 2);
  bf16* txt_bf = (bf16*)alloc((size_t)BDIM * 512 * 2);
  bf16* ipw_bf = (bf16*)alloc((size_t)2 * 512 * 512 * 2);
  bf16* wv_bf  = (bf16*)alloc((size_t)6 * 512 * 512 * 2);
  bf16* ao_bf  = (bf16*)alloc((size_t)6 * 512 * 512 * 2);
  bf16* f1_bf  = (bf16*)alloc((size_t)6 * 2048 * 512 * 2);
  bf16* f2_bf  = (bf16*)alloc((size_t)6 * 512 * 2048 * 2);
  bf16* op_bf  = (bf16*)alloc((size_t)2 * 512 * 512 * 2);
  bf16* x      = (bf16*)alloc((size_t)BDIM * 512 * 2);
  bf16* xn     = (bf16*)alloc((size_t)BDIM * 512 * 2);
  bf16* t1     = (bf16*)alloc((size_t)BDIM * 2048 * 2);
  bf16* gen0   = (bf16*)alloc((size_t)BDIM * 512 * 2);
  float* ph    = (float*)alloc(1024 * 4);
  float* pout  = (float*)alloc(1024 * 4);

  auto cvt = [&](const float* s, bf16* d, int n) {
    int n4 = n / 4;
    cvt_f32_bf16<<<(n4 + 255) / 256, 256, 0, stream>>>(s, d, n4);
  };
  cvt(img, img_bf, BDIM * 512);
  cvt(txt, txt_bf, BDIM * 512);
  cvt(ipw, ipw_bf, 2 * 512 * 512);
  cvt_wv<<<1536, 256, 0, stream>>>(qkvw, wv_bf);
  cvt(aow, ao_bf, 6 * 512 * 512);
  cvt(f1w, f1_bf, 6 * 2048 * 512);
  cvt(f2w, f2_bf, 6 * 512 * 2048);
  cvt(opw, op_bf, 2 * 512 * 512);

  auto gemm = [&](const bf16* A, int lda, const bf16* W, const float* bias,
                  bf16* C, int ldc, int N, int K, bool gelu) {
    dim3 grid(BDIM / 128, N / 128);
    if (gelu)
      gemm_bf16<true><<<grid, 256, 0, stream>>>(A, lda, W, bias, C, ldc, K);
    else
      gemm_bf16<false><<<grid, 256, 0, stream>>>(A, lda, W, bias, C, ldc, K);
  };

  for (int i = 0; i < 2; ++i) {
    const bf16* src = i ? txt_bf : img_bf;
    const bf16* tgt = i ? img_bf : txt_bf;
    gemm(src, 512, ipw_bf + i * 262144, ipb + i * 512, x, 512, 512, 512, false);
    for (int l = 0; l < 3; ++l) {
      int il = i * 3 + l;
      bf16* vtmp = t1;                        // B x 512
      bf16* attn = t1 + (size_t)BDIM * 512;   // B x 512
      // v = tgt @ wv^T + bv   (softmax over single kv position == 1 -> attn = v)
      gemm(tgt, 512, wv_bf + il * 262144, qkvb + il * 1536 + 1024, vtmp, 512, 512, 512, false);
      // attn_out = v @ ao^T + ao_b
      gemm(vtmp, 512, ao_bf + il * 262144, aob + il * 512, attn, 512, 512, 512, false);
      // x = LN(x + attn)
      add_ln<<<BDIM / 4, 256, 0, stream>>>(x, attn, ln1g + il * 512, ln1b + il * 512, xn);
      // h = gelu(x @ f1^T + b)
      gemm(xn, 512, f1_bf + il * 1048576, f1b + il * 2048, t1, 2048, 2048, 512, true);
      // y = h @ f2^T + b  (into x buffer, old x already consumed)
      gemm(t1, 2048, f2_bf + il * 1048576, f2b + il * 512, x, 512, 512, 2048, false);
      // x = LN(xn + y)
      add_ln<<<BDIM / 4, 256, 0, stream>>>(xn, x, ln2g + il * 512, ln2b + il * 512, x);
    }
    bf16* gdst = i ? xn : gen0;   // gen0 = gen_text, xn = gen_img
    gemm(x, 512, op_bf + i * 262144, opb + i * 512, gdst, 512, 512, 512, false);
  }

  prior_fc1<<<256, 256, 0, stream>>>(pemb, pw1, pb1, ph);
  prior_fc2<<<256, 256, 0, stream>>>(ph, pw2, pb2, pout);

  combine<<<(BDIM * 128 + 255) / 256, 256, 0, stream>>>(img, txt, gen0, xn, pout, mt, rw, out);
}